// Round 6
// baseline (111.379 us; speedup 1.0000x reference)
//
#include <hip/hip_runtime.h>

// MyAttention: B=2, T=4096, D=768, DO=256, H=4, DH=64, W2=15
#define TPC   4110            // T + 14 (padded seq)
#define MROWS 8220            // B * TPC
#define MTOT  8235            // + 15 pos rows
#define KD    768

typedef __attribute__((ext_vector_type(8))) short short8;
typedef __attribute__((ext_vector_type(4))) float f32x4;

#define LOAD_LDS16(gp, lp)                                                   \
  __builtin_amdgcn_global_load_lds(                                          \
      (const __attribute__((address_space(1))) void*)(gp),                   \
      (__attribute__((address_space(3))) void*)(lp), 16, 0, 0)

__device__ inline unsigned bfr(float x) {
  unsigned u = __float_as_uint(x);
  return (u + 0x7FFFu + ((u >> 16) & 1u)) >> 16;   // RNE fp32->bf16
}
__device__ inline unsigned pack2(float a, float b) {
  return bfr(a) | (bfr(b) << 16);
}
// round-half-up pack (cheap, ~RNE accuracy): low short <- a, high <- b
__device__ inline unsigned pack2h(float a, float b) {
  return ((__float_as_uint(a) + 0x8000u) >> 16) |
         ((__float_as_uint(b) + 0x8000u) & 0xffff0000u);
}
__device__ inline float bflo(unsigned u) { return __uint_as_float(u << 16); }
__device__ inline float bfhi(unsigned u) { return __uint_as_float(u & 0xffff0000u); }

// ---------------------------------------------------------------------------
// Prep: cast W ([Wq;Wv] 512x768) to bf16 + write the 64B zero page used by
// the GEMM for pad-row staging. 192 blocks, ~0.3 us.
__global__ __launch_bounds__(256) void cast_w(
    const float* __restrict__ Wq, const float* __restrict__ Wv,
    ushort* __restrict__ Wbf, float* __restrict__ zpage) {
  int gid = blockIdx.x * 256 + threadIdx.x;
  if (gid == 0) {
    *(uint4*)(zpage) = make_uint4(0, 0, 0, 0);
    *(uint4*)(zpage + 4) = make_uint4(0, 0, 0, 0);
    *(uint4*)(zpage + 8) = make_uint4(0, 0, 0, 0);
    *(uint4*)(zpage + 12) = make_uint4(0, 0, 0, 0);
  }
  int row = gid / 96, c = (gid - row * 96) * 8;
  const float* src = (row < 256) ? Wq + (size_t)row * KD + c
                                 : Wv + (size_t)(row - 256) * KD + c;
  float4 f0 = *(const float4*)src;
  float4 f1 = *(const float4*)(src + 4);
  uint4 o;
  o.x = pack2(f0.x, f0.y); o.y = pack2(f0.z, f0.w);
  o.z = pack2(f1.x, f1.y); o.w = pack2(f1.z, f1.w);
  *(uint4*)(Wbf + (size_t)row * KD + c) = o;
}

// ---------------------------------------------------------------------------
// Fused cast+GEMM: C[MTOT][512] = A @ [Wq;Wv]^T. A is read DIRECTLY as fp32
// (zero-padded inputs + pos rows) via global_load_lds into a fp32 LDS tile;
// fragments are converted to bf16 in-register at read time (round-half-up).
// 64(m) x 128(n) tiles, BK=64, 516 blocks. fp32 A rows (256B = 0 mod 32
// banks) are XOR-swizzled by row&15 in 16B chunks; bf16 B rows by row&7
// (as R5). bf16 outputs in attention layout q/v [B][H][TPC][64].
__global__ __launch_bounds__(256) void gemm_fused(
    const float* __restrict__ inp, const float* __restrict__ pos,
    const float* __restrict__ zpage, const ushort* __restrict__ Wbf,
    const float* __restrict__ bq, const float* __restrict__ bv,
    ushort* __restrict__ q_out, ushort* __restrict__ v_out,
    ushort* __restrict__ pos_q, ushort* __restrict__ pos_v) {
  __shared__ float  AlF[64 * 64];   // 16 KB (fp32, BK=64)
  __shared__ ushort Bl[128 * 64];   // 16 KB (bf16)
  const int tid = threadIdx.x;
  const int wave = tid >> 6, lane = tid & 63;
  const int ns = blockIdx.x;            // 0..3 (0-1 -> q, 2-3 -> v)
  const int m0 = blockIdx.y * 64;
  const int wm = wave & 1, wn = wave >> 1;
  const int fr = lane & 15, quad = lane >> 4;

  // ---- A staging: 1024 chunks/iter (64 rows x 16 chunks of 16B), 4 issues.
  // chunk c -> row=c>>4, kc=c&15; global source chunk = kc ^ (row&15).
  const float* agp[4];
  bool aval[4];
  #pragma unroll
  for (int i = 0; i < 4; i++) {
    int c = i * 256 + tid, row = c >> 4, kc = c & 15;
    int m = m0 + row;
    int woff = (kc ^ (row & 15)) * 4;
    if (m < MROWS) {
      int b = m / TPC, t = m - b * TPC - 7;
      aval[i] = (t >= 0 && t < 4096);
      agp[i] = aval[i] ? inp + ((size_t)b * 4096 + t) * KD + woff : zpage;
    } else if (m < MTOT) {
      aval[i] = true;
      agp[i] = pos + (size_t)(m - MROWS) * KD + woff;
    } else {
      aval[i] = false;
      agp[i] = zpage;
    }
  }
  // ---- B staging: 1024 chunks/iter (128 rows x 8 chunks), 4 issues (as R5).
  const ushort* bg[4];
  #pragma unroll
  for (int i = 0; i < 4; i++) {
    int c = i * 256 + tid, row = c >> 3, kq = c & 7;
    bg[i] = Wbf + (size_t)(ns * 128 + row) * KD + ((kq ^ (row & 7)) * 8);
  }
  float* alw[4];
  ushort* blw[4];
  #pragma unroll
  for (int i = 0; i < 4; i++) {
    alw[i] = AlF + (i * 256 + wave * 64) * 4;        // HW adds lane*16B
    blw[i] = Bl + (i * 256 + wave * 64) * 8;
  }

  f32x4 acc[2][4];
  #pragma unroll
  for (int i = 0; i < 2; i++)
    #pragma unroll
    for (int j = 0; j < 4; j++) acc[i][j] = 0.0f;

  for (int k0 = 0; k0 < KD; k0 += 64) {
    #pragma unroll
    for (int i = 0; i < 4; i++) LOAD_LDS16(agp[i] + (aval[i] ? k0 : 0), alw[i]);
    #pragma unroll
    for (int i = 0; i < 4; i++) LOAD_LDS16(bg[i] + k0, blw[i]);
    __syncthreads();

    short8 af[2][2], bf[2][4];
    #pragma unroll
    for (int ks = 0; ks < 2; ks++) {
      // A: row r, logical 16B chunks (ks*8 + quad*2 + {0,1}) ^ fr (r&15==fr)
      #pragma unroll
      for (int i = 0; i < 2; i++) {
        const int r = wm * 32 + i * 16 + fr;
        float4 c0 = *(const float4*)(AlF + r * 64 + (((ks * 8) + quad * 2 + 0) ^ fr) * 4);
        float4 c1 = *(const float4*)(AlF + r * 64 + (((ks * 8) + quad * 2 + 1) ^ fr) * 4);
        union { unsigned u[4]; short8 s; } cv;
        cv.u[0] = pack2h(c0.x, c0.y); cv.u[1] = pack2h(c0.z, c0.w);
        cv.u[2] = pack2h(c1.x, c1.y); cv.u[3] = pack2h(c1.z, c1.w);
        af[ks][i] = cv.s;
      }
      const int e = ((ks * 4 + quad) ^ (fr & 7)) * 8;   // B un-swizzle
      #pragma unroll
      for (int j = 0; j < 4; j++)
        bf[ks][j] = *(const short8*)(Bl + (wn * 64 + j * 16 + fr) * 64 + e);
    }
    #pragma unroll
    for (int ks = 0; ks < 2; ks++)
      #pragma unroll
      for (int i = 0; i < 2; i++)
        #pragma unroll
        for (int j = 0; j < 4; j++)
          acc[i][j] = __builtin_amdgcn_mfma_f32_16x16x32_bf16(
              af[ks][i], bf[ks][j], acc[i][j], 0, 0, 0);
    __syncthreads();
  }

  // epilogue: C/D layout col=lane&15 (n), row=quad*4+reg (m); bf16 stores
  const float* bias = (ns < 2) ? bq : bv;
  ushort* outp = (ns < 2) ? q_out : v_out;
  ushort* posp = (ns < 2) ? pos_q : pos_v;
  const int wbase = (ns & 1) * 128;
  #pragma unroll
  for (int j = 0; j < 4; j++) {
    const int colq = wbase + wn * 64 + j * 16 + fr;   // 0..255
    const int h = colq >> 6, d = colq & 63;
    const float bj = bias[colq];
    #pragma unroll
    for (int i = 0; i < 2; i++) {
      const int mb = m0 + wm * 32 + i * 16 + quad * 4;
      #pragma unroll
      for (int r = 0; r < 4; r++) {
        const int m = mb + r;
        if (m < MROWS) {
          int b = m / TPC, tp = m - b * TPC;
          outp[(((size_t)(b * 4 + h)) * TPC + tp) * 64 + d] =
              (ushort)bfr(acc[i][j][r] + bj);
        } else if (m < MTOT) {
          posp[(m - MROWS) * 256 + colq] = (ushort)bfr(acc[i][j][r]);
        }
      }
    }
  }
}

// ---------------------------------------------------------------------------
// Windowed attention. bf16 k/v/pos in ([B][H][TPC][64] layout -> contiguous
// 78-row slab per block), converted to fp32 once at LDS staging.
// Block = (b, h, 64-t tile); thread = (t_local, quarter of DH); 2-step
// 4-lane shuffle for the dot. fp32 output. ~17 MB traffic, near BW floor.
__global__ __launch_bounds__(256) void win_attn4(
    const ushort* __restrict__ q_out, const ushort* __restrict__ v_out,
    const ushort* __restrict__ pos_q, const ushort* __restrict__ pos_v,
    float* __restrict__ out) {
  __shared__ __align__(16) float ks[78][68];
  __shared__ __align__(16) float vs[78][68];
  __shared__ __align__(16) float pq[15][68];
  __shared__ __align__(16) float pv[15][68];
  const int tid = threadIdx.x;
  const int bh = blockIdx.x >> 6, tile = blockIdx.x & 63;
  const int b = bh >> 2, h = bh & 3;
  const int t0 = tile * 64;

  const size_t slab = (((size_t)(b * 4 + h)) * TPC + t0) * 64;
  for (int idx = tid; idx < 624; idx += 256) {
    int row = idx >> 3, c8 = (idx & 7) * 8;
    uint4 kc = *(const uint4*)(q_out + slab + idx * 8);
    ks[row][c8 + 0] = bflo(kc.x); ks[row][c8 + 1] = bfhi(kc.x);
    ks[row][c8 + 2] = bflo(kc.y); ks[row][c8 + 3] = bfhi(kc.y);
    ks[row][c8 + 4] = bflo(kc.z); ks[row][c8 + 5] = bfhi(kc.z);
    ks[row][c8 + 6] = bflo(kc.w); ks[row][c8 + 7] = bfhi(kc.w);
    uint4 vc = *(const uint4*)(v_out + slab + idx * 8);
    vs[row][c8 + 0] = bflo(vc.x); vs[row][c8 + 1] = bfhi(vc.x);
    vs[row][c8 + 2] = bflo(vc.y); vs[row][c8 + 3] = bfhi(vc.y);
    vs[row][c8 + 4] = bflo(vc.z); vs[row][c8 + 5] = bfhi(vc.z);
    vs[row][c8 + 6] = bflo(vc.w); vs[row][c8 + 7] = bfhi(vc.w);
  }
  if (tid < 120) {
    int row = tid >> 3, c8 = (tid & 7) * 8;
    uint4 qc = *(const uint4*)(pos_q + row * 256 + h * 64 + c8);
    pq[row][c8 + 0] = bflo(qc.x); pq[row][c8 + 1] = bfhi(qc.x);
    pq[row][c8 + 2] = bflo(qc.y); pq[row][c8 + 3] = bfhi(qc.y);
    pq[row][c8 + 4] = bflo(qc.z); pq[row][c8 + 5] = bfhi(qc.z);
    pq[row][c8 + 6] = bflo(qc.w); pq[row][c8 + 7] = bfhi(qc.w);
    uint4 vc = *(const uint4*)(pos_v + row * 256 + h * 64 + c8);
    pv[row][c8 + 0] = bflo(vc.x); pv[row][c8 + 1] = bfhi(vc.x);
    pv[row][c8 + 2] = bflo(vc.y); pv[row][c8 + 3] = bfhi(vc.y);
    pv[row][c8 + 4] = bflo(vc.z); pv[row][c8 + 5] = bfhi(vc.z);
    pv[row][c8 + 6] = bflo(vc.w); pv[row][c8 + 7] = bfhi(vc.w);
  }
  __syncthreads();

  const int tl = tid >> 2, qtr = tid & 3, d0 = qtr * 16;
  float4 qv[4];
  #pragma unroll
  for (int c = 0; c < 4; c++) qv[c] = *(float4*)&ks[tl + 7][d0 + c * 4];
  float4 ctx[4];
  #pragma unroll
  for (int c = 0; c < 4; c++) ctx[c] = make_float4(0.f, 0.f, 0.f, 0.f);

  #pragma unroll
  for (int w = 0; w < 15; w++) {
    float p = 0.f;
    #pragma unroll
    for (int c = 0; c < 4; c++) {
      float4 kk = *(float4*)&ks[tl + w][d0 + c * 4];
      float4 pp = *(float4*)&pq[w][d0 + c * 4];
      p += qv[c].x * (kk.x + pp.x) + qv[c].y * (kk.y + pp.y) +
           qv[c].z * (kk.z + pp.z) + qv[c].w * (kk.w + pp.w);
    }
    p += __shfl_xor(p, 1, 64);
    p += __shfl_xor(p, 2, 64);
    #pragma unroll
    for (int c = 0; c < 4; c++) {
      float4 vv = *(float4*)&vs[tl + w][d0 + c * 4];
      float4 pp = *(float4*)&pv[w][d0 + c * 4];
      ctx[c].x += p * (vv.x + pp.x);
      ctx[c].y += p * (vv.y + pp.y);
      ctx[c].z += p * (vv.z + pp.z);
      ctx[c].w += p * (vv.w + pp.w);
    }
  }
  size_t oo = ((size_t)(b * 4096 + t0 + tl)) * 256 + h * 64 + d0;
  #pragma unroll
  for (int c = 0; c < 4; c++) *(float4*)(out + oo + c * 4) = ctx[c];
}

// ---------------------------------------------------------------------------
extern "C" void kernel_launch(void* const* d_in, const int* in_sizes, int n_in,
                              void* d_out, int out_size, void* d_ws,
                              size_t ws_size, hipStream_t stream) {
  const float* inp = (const float*)d_in[0];
  const float* Wq  = (const float*)d_in[1];
  const float* bq  = (const float*)d_in[2];
  const float* Wv  = (const float*)d_in[3];
  const float* bv  = (const float*)d_in[4];
  const float* pos = (const float*)d_in[5];
  float* out = (float*)d_out;

  // ws layout (bytes): Wbf 786,432 | zpage 64+pad | q_out 4,208,640 |
  // v_out 4,208,640 | pos_q 7,680 | pos_v 7,680  -> ~9.2 MB
  char* ws = (char*)d_ws;
  ushort* Wbf   = (ushort*)ws;
  float*  zpage = (float*)(ws + 786432);
  ushort* q_out = (ushort*)(ws + 786688);     // [B][H][TPC][64] bf16
  ushort* v_out = (ushort*)(ws + 4995328);
  ushort* pos_q = (ushort*)(ws + 9203968);    // [15][256] bf16
  ushort* pos_v = (ushort*)(ws + 9211648);

  hipLaunchKernelGGL(cast_w, dim3(192), dim3(256), 0, stream,
                     Wq, Wv, Wbf, zpage);
  hipLaunchKernelGGL(gemm_fused, dim3(4, 129), dim3(256), 0, stream,
                     inp, pos, zpage, Wbf, bq, bv, q_out, v_out, pos_q, pos_v);
  hipLaunchKernelGGL(win_attn4, dim3(2 * 4 * 64), dim3(256), 0, stream,
                     q_out, v_out, pos_q, pos_v, out);
}

// Round 7
// 109.354 us; speedup vs baseline: 1.0185x; 1.0185x over previous
//
#include <hip/hip_runtime.h>

// MyAttention: B=2, T=4096, D=768, DO=256, H=4, DH=64, W2=15
// Final structure (R5, best measured): cast_ab -> gemm_bf16 -> win_attn4.
// R6 lesson: fusing the A-cast into the GEMM regresses (fp32 A re-read x4
// n-strips ~100MB > 25.6MB cast round-trip; conversion VALU lands on the
// lgkmcnt->MFMA critical path). Cast-once-reuse-many wins at k=4 reuses.
#define TPC   4110            // T + 14 (padded seq)
#define MROWS 8220            // B * TPC
#define MTOT  8235            // + 15 pos rows
#define MPAD  8320            // 130 * 64
#define KD    768

typedef __attribute__((ext_vector_type(8))) short short8;
typedef __attribute__((ext_vector_type(4))) float f32x4;

#define LOAD_LDS16(gp, lp)                                                   \
  __builtin_amdgcn_global_load_lds(                                          \
      (const __attribute__((address_space(1))) void*)(gp),                   \
      (__attribute__((address_space(3))) void*)(lp), 16, 0, 0)

__device__ inline unsigned bfr(float x) {
  unsigned u = __float_as_uint(x);
  return (u + 0x7FFFu + ((u >> 16) & 1u)) >> 16;   // RNE fp32->bf16
}
__device__ inline unsigned pack2(float a, float b) {
  return bfr(a) | (bfr(b) << 16);
}
__device__ inline float bflo(unsigned u) { return __uint_as_float(u << 16); }
__device__ inline float bfhi(unsigned u) { return __uint_as_float(u & 0xffff0000u); }

// ---------------------------------------------------------------------------
// Pass 1: cast A (zero-padded inputs + 15 pos rows, MPAD x 768) and W
// ([Wq;Wv], 512 x 768) to bf16. One 16B chunk (8 bf16) per thread.
// Pure streaming, ~41 MB -> BW-bound (~6.5 us), at floor.
__global__ __launch_bounds__(256) void cast_ab(
    const float* __restrict__ inp, const float* __restrict__ Wq,
    const float* __restrict__ Wv, const float* __restrict__ pos,
    ushort* __restrict__ Abf, ushort* __restrict__ Wbf) {
  const int ACH = MPAD * 96;
  int gid = blockIdx.x * 256 + threadIdx.x;
  const float* src = nullptr;
  ushort* dst;
  if (gid < ACH) {
    int row = gid / 96, c = (gid - row * 96) * 8;
    dst = Abf + (size_t)row * KD + c;
    if (row < MROWS) {
      int b = row / TPC, t = row - b * TPC - 7;
      if (t >= 0 && t < 4096) src = inp + ((size_t)b * 4096 + t) * KD + c;
    } else if (row < MTOT) {
      src = pos + (size_t)(row - MROWS) * KD + c;
    }
  } else {
    int wid = gid - ACH;
    if (wid >= 512 * 96) return;
    int row = wid / 96, c = (wid - row * 96) * 8;
    dst = Wbf + (size_t)row * KD + c;
    src = (row < 256) ? Wq + (size_t)row * KD + c
                      : Wv + (size_t)(row - 256) * KD + c;
  }
  uint4 o;
  if (src) {
    float4 f0 = *(const float4*)src;
    float4 f1 = *(const float4*)(src + 4);
    o.x = pack2(f0.x, f0.y); o.y = pack2(f0.z, f0.w);
    o.z = pack2(f1.x, f1.y); o.w = pack2(f1.z, f1.w);
  } else {
    o.x = o.y = o.z = o.w = 0u;
  }
  *(uint4*)dst = o;
}

// ---------------------------------------------------------------------------
// Pass 2: C[MPAD][512] = Abf @ Wbf^T. bf16 MFMA 16x16x32, 64(m) x 128(n)
// tiles, BK=64 (12 barrier-iters; halves the syncthreads vmcnt-drain stalls
// vs BK=32), 520 blocks (~2/CU), global_load_lds width-16 staging.
// k-chunks XOR-swizzled by (row&7) inside each 128B row so fragment
// ds_read_b128 stays at the wave64 bank minimum (128B row stride would
// otherwise put 16 lanes on one bank group).
// bf16 outputs in attention layout q/v [B][H][TPC][64]; pos -> [15][256].
__global__ __launch_bounds__(256) void gemm_bf16(
    const ushort* __restrict__ Abf, const ushort* __restrict__ Wbf,
    const float* __restrict__ bq, const float* __restrict__ bv,
    ushort* __restrict__ q_out, ushort* __restrict__ v_out,
    ushort* __restrict__ pos_q, ushort* __restrict__ pos_v) {
  __shared__ ushort Al[64 * 64];    // 8 KB
  __shared__ ushort Bl[128 * 64];   // 16 KB
  const int tid = threadIdx.x;
  const int wave = tid >> 6, lane = tid & 63;
  const int ns = blockIdx.x;            // 0..3 (0-1 -> q, 2-3 -> v)
  const int m0 = blockIdx.y * 64;
  const int wm = wave & 1, wn = wave >> 1;
  const int fr = lane & 15, quad = lane >> 4;

  // staging: chunk c -> row = c>>3, logical k-chunk kq = c&7,
  // swizzled global source chunk = kq ^ (row&7).
  const ushort* ag[2];
  #pragma unroll
  for (int i = 0; i < 2; i++) {
    int c = i * 256 + tid, row = c >> 3, kq = c & 7;
    ag[i] = Abf + (size_t)(m0 + row) * KD + ((kq ^ (row & 7)) * 8);
  }
  const ushort* bg[4];
  #pragma unroll
  for (int i = 0; i < 4; i++) {
    int c = i * 256 + tid, row = c >> 3, kq = c & 7;
    bg[i] = Wbf + (size_t)(ns * 128 + row) * KD + ((kq ^ (row & 7)) * 8);
  }
  ushort* al[2];
  ushort* bl[4];
  #pragma unroll
  for (int i = 0; i < 2; i++) al[i] = Al + (i * 256 + wave * 64) * 8;
  #pragma unroll
  for (int i = 0; i < 4; i++) bl[i] = Bl + (i * 256 + wave * 64) * 8;

  f32x4 acc[2][4];
  #pragma unroll
  for (int i = 0; i < 2; i++)
    #pragma unroll
    for (int j = 0; j < 4; j++) acc[i][j] = 0.0f;

  for (int k0 = 0; k0 < KD; k0 += 64) {
    #pragma unroll
    for (int i = 0; i < 2; i++) LOAD_LDS16(ag[i] + k0, al[i]);
    #pragma unroll
    for (int i = 0; i < 4; i++) LOAD_LDS16(bg[i] + k0, bl[i]);
    __syncthreads();
    short8 af[2][2], bf[2][4];
    #pragma unroll
    for (int ks = 0; ks < 2; ks++) {
      const int e = ((ks * 4 + quad) ^ (fr & 7)) * 8;   // un-swizzle
      #pragma unroll
      for (int i = 0; i < 2; i++)
        af[ks][i] = *(const short8*)(Al + (wm * 32 + i * 16 + fr) * 64 + e);
      #pragma unroll
      for (int j = 0; j < 4; j++)
        bf[ks][j] = *(const short8*)(Bl + (wn * 64 + j * 16 + fr) * 64 + e);
    }
    #pragma unroll
    for (int ks = 0; ks < 2; ks++)
      #pragma unroll
      for (int i = 0; i < 2; i++)
        #pragma unroll
        for (int j = 0; j < 4; j++)
          acc[i][j] = __builtin_amdgcn_mfma_f32_16x16x32_bf16(
              af[ks][i], bf[ks][j], acc[i][j], 0, 0, 0);
    __syncthreads();
  }

  // epilogue: C/D layout col=lane&15 (n), row=quad*4+reg (m); bf16 stores
  const float* bias = (ns < 2) ? bq : bv;
  ushort* outp = (ns < 2) ? q_out : v_out;
  ushort* posp = (ns < 2) ? pos_q : pos_v;
  const int wbase = (ns & 1) * 128;
  #pragma unroll
  for (int j = 0; j < 4; j++) {
    const int colq = wbase + wn * 64 + j * 16 + fr;   // 0..255
    const int h = colq >> 6, d = colq & 63;
    const float bj = bias[colq];
    #pragma unroll
    for (int i = 0; i < 2; i++) {
      const int mb = m0 + wm * 32 + i * 16 + quad * 4;
      #pragma unroll
      for (int r = 0; r < 4; r++) {
        const int m = mb + r;
        if (m < MROWS) {
          int b = m / TPC, tp = m - b * TPC;
          outp[(((size_t)(b * 4 + h)) * TPC + tp) * 64 + d] =
              (ushort)bfr(acc[i][j][r] + bj);
        } else if (m < MTOT) {
          posp[(m - MROWS) * 256 + colq] = (ushort)bfr(acc[i][j][r]);
        }
      }
    }
  }
}

// ---------------------------------------------------------------------------
// Pass 3: windowed attention. bf16 k/v/pos in ([B][H][TPC][64] layout ->
// contiguous 78-row slab per block), converted to fp32 once at LDS staging.
// Block = (b, h, 64-t tile); thread = (t_local, quarter of DH); 2-step
// 4-lane shuffle for the dot. fp32 output. ~17 MB traffic, near BW floor.
__global__ __launch_bounds__(256) void win_attn4(
    const ushort* __restrict__ q_out, const ushort* __restrict__ v_out,
    const ushort* __restrict__ pos_q, const ushort* __restrict__ pos_v,
    float* __restrict__ out) {
  __shared__ __align__(16) float ks[78][68];
  __shared__ __align__(16) float vs[78][68];
  __shared__ __align__(16) float pq[15][68];
  __shared__ __align__(16) float pv[15][68];
  const int tid = threadIdx.x;
  const int bh = blockIdx.x >> 6, tile = blockIdx.x & 63;
  const int b = bh >> 2, h = bh & 3;
  const int t0 = tile * 64;

  const size_t slab = (((size_t)(b * 4 + h)) * TPC + t0) * 64;
  for (int idx = tid; idx < 624; idx += 256) {
    int row = idx >> 3, c8 = (idx & 7) * 8;
    uint4 kc = *(const uint4*)(q_out + slab + idx * 8);
    ks[row][c8 + 0] = bflo(kc.x); ks[row][c8 + 1] = bfhi(kc.x);
    ks[row][c8 + 2] = bflo(kc.y); ks[row][c8 + 3] = bfhi(kc.y);
    ks[row][c8 + 4] = bflo(kc.z); ks[row][c8 + 5] = bfhi(kc.z);
    ks[row][c8 + 6] = bflo(kc.w); ks[row][c8 + 7] = bfhi(kc.w);
    uint4 vc = *(const uint4*)(v_out + slab + idx * 8);
    vs[row][c8 + 0] = bflo(vc.x); vs[row][c8 + 1] = bfhi(vc.x);
    vs[row][c8 + 2] = bflo(vc.y); vs[row][c8 + 3] = bfhi(vc.y);
    vs[row][c8 + 4] = bflo(vc.z); vs[row][c8 + 5] = bfhi(vc.z);
    vs[row][c8 + 6] = bflo(vc.w); vs[row][c8 + 7] = bfhi(vc.w);
  }
  if (tid < 120) {
    int row = tid >> 3, c8 = (tid & 7) * 8;
    uint4 qc = *(const uint4*)(pos_q + row * 256 + h * 64 + c8);
    pq[row][c8 + 0] = bflo(qc.x); pq[row][c8 + 1] = bfhi(qc.x);
    pq[row][c8 + 2] = bflo(qc.y); pq[row][c8 + 3] = bfhi(qc.y);
    pq[row][c8 + 4] = bflo(qc.z); pq[row][c8 + 5] = bfhi(qc.z);
    pq[row][c8 + 6] = bflo(qc.w); pq[row][c8 + 7] = bfhi(qc.w);
    uint4 vc = *(const uint4*)(pos_v + row * 256 + h * 64 + c8);
    pv[row][c8 + 0] = bflo(vc.x); pv[row][c8 + 1] = bfhi(vc.x);
    pv[row][c8 + 2] = bflo(vc.y); pv[row][c8 + 3] = bfhi(vc.y);
    pv[row][c8 + 4] = bflo(vc.z); pv[row][c8 + 5] = bfhi(vc.z);
    pv[row][c8 + 6] = bflo(vc.w); pv[row][c8 + 7] = bfhi(vc.w);
  }
  __syncthreads();

  const int tl = tid >> 2, qtr = tid & 3, d0 = qtr * 16;
  float4 qv[4];
  #pragma unroll
  for (int c = 0; c < 4; c++) qv[c] = *(float4*)&ks[tl + 7][d0 + c * 4];
  float4 ctx[4];
  #pragma unroll
  for (int c = 0; c < 4; c++) ctx[c] = make_float4(0.f, 0.f, 0.f, 0.f);

  #pragma unroll
  for (int w = 0; w < 15; w++) {
    float p = 0.f;
    #pragma unroll
    for (int c = 0; c < 4; c++) {
      float4 kk = *(float4*)&ks[tl + w][d0 + c * 4];
      float4 pp = *(float4*)&pq[w][d0 + c * 4];
      p += qv[c].x * (kk.x + pp.x) + qv[c].y * (kk.y + pp.y) +
           qv[c].z * (kk.z + pp.z) + qv[c].w * (kk.w + pp.w);
    }
    p += __shfl_xor(p, 1, 64);
    p += __shfl_xor(p, 2, 64);
    #pragma unroll
    for (int c = 0; c < 4; c++) {
      float4 vv = *(float4*)&vs[tl + w][d0 + c * 4];
      float4 pp = *(float4*)&pv[w][d0 + c * 4];
      ctx[c].x += p * (vv.x + pp.x);
      ctx[c].y += p * (vv.y + pp.y);
      ctx[c].z += p * (vv.z + pp.z);
      ctx[c].w += p * (vv.w + pp.w);
    }
  }
  size_t oo = ((size_t)(b * 4096 + t0 + tl)) * 256 + h * 64 + d0;
  #pragma unroll
  for (int c = 0; c < 4; c++) *(float4*)(out + oo + c * 4) = ctx[c];
}

// ---------------------------------------------------------------------------
extern "C" void kernel_launch(void* const* d_in, const int* in_sizes, int n_in,
                              void* d_out, int out_size, void* d_ws,
                              size_t ws_size, hipStream_t stream) {
  const float* inp = (const float*)d_in[0];
  const float* Wq  = (const float*)d_in[1];
  const float* bq  = (const float*)d_in[2];
  const float* Wv  = (const float*)d_in[3];
  const float* bv  = (const float*)d_in[4];
  const float* pos = (const float*)d_in[5];
  float* out = (float*)d_out;

  // ws layout (bytes): Abf 12,779,520 | Wbf 786,432 | q_out 4,208,640 |
  // v_out 4,208,640 | pos_q 7,680 | pos_v 7,680  -> ~22.0 MB
  char* ws = (char*)d_ws;
  ushort* Abf   = (ushort*)ws;
  ushort* Wbf   = (ushort*)(ws + 12779520);
  ushort* q_out = (ushort*)(ws + 13565952);   // [B][H][TPC][64] bf16
  ushort* v_out = (ushort*)(ws + 17774592);
  ushort* pos_q = (ushort*)(ws + 21983232);   // [15][256] bf16
  ushort* pos_v = (ushort*)(ws + 21990912);

  const int cast_chunks = MPAD * 96 + 512 * 96;        // 847,872
  hipLaunchKernelGGL(cast_ab, dim3(cast_chunks / 256), dim3(256), 0, stream,
                     inp, Wq, Wv, pos, Abf, Wbf);
  hipLaunchKernelGGL(gemm_bf16, dim3(4, MPAD / 64), dim3(256), 0, stream,
                     Abf, Wbf, bq, bv, q_out, v_out, pos_q, pos_v);
  hipLaunchKernelGGL(win_attn4, dim3(2 * 4 * 64), dim3(256), 0, stream,
                     q_out, v_out, pos_q, pos_v, out);
}